// Round 2
// baseline (623.383 us; speedup 1.0000x reference)
//
#include <hip/hip_runtime.h>
#include <hip/hip_bf16.h>
#include <stdint.h>

#define NB 32
#define NR 2048
#define NC 64
#define NO 64
#define NK 16

#define WAIT_VMCNT6 do { asm volatile("s_waitcnt vmcnt(6)" ::: "memory"); __builtin_amdgcn_sched_barrier(0); } while (0)
#define WAIT_VMCNT0 do { asm volatile("s_waitcnt vmcnt(0)" ::: "memory"); __builtin_amdgcn_sched_barrier(0); } while (0)
#define WAIT_LGKM0  do { asm volatile("s_waitcnt lgkmcnt(0)" ::: "memory"); __builtin_amdgcn_sched_barrier(0); } while (0)

__device__ __forceinline__ uint32_t f2bf(float f) {
  uint32_t u = __builtin_bit_cast(uint32_t, f);
  return (u + 0x7fffu + ((u >> 16) & 1u)) >> 16;  // RNE
}
__device__ __forceinline__ uint32_t packbf2(float lo, float hi) {
  return f2bf(lo) | (f2bf(hi) << 16);
}

__device__ __forceinline__ void gload_lds16(const float* g, float* l) {
  __builtin_amdgcn_global_load_lds(
      (const __attribute__((address_space(1))) void*)g,
      (__attribute__((address_space(3))) void*)l, 16, 0, 0);
}

// x[b][r][c] -> xT[r][c][b]
__global__ __launch_bounds__(256) void transpose_x(const float* __restrict__ x,
                                                   float* __restrict__ xT) {
  __shared__ float tile[32][65];
  const int r = blockIdx.x, t = threadIdx.x;
  {
    const int b = t >> 3, c0 = (t & 7) << 3;
    const float* xp = x + ((size_t)b * NR + r) * NC + c0;
    float4 v0 = *(const float4*)xp;
    float4 v1 = *(const float4*)(xp + 4);
    tile[b][c0 + 0] = v0.x; tile[b][c0 + 1] = v0.y; tile[b][c0 + 2] = v0.z; tile[b][c0 + 3] = v0.w;
    tile[b][c0 + 4] = v1.x; tile[b][c0 + 5] = v1.y; tile[b][c0 + 6] = v1.z; tile[b][c0 + 7] = v1.w;
  }
  __syncthreads();
  {
    const int c = t >> 2, b0 = (t & 3) << 3;
    float4 w0 = make_float4(tile[b0 + 0][c], tile[b0 + 1][c], tile[b0 + 2][c], tile[b0 + 3][c]);
    float4 w1 = make_float4(tile[b0 + 4][c], tile[b0 + 5][c], tile[b0 + 6][c], tile[b0 + 7][c]);
    float* op = xT + ((size_t)r * NC + c) * NB + b0;
    *(float4*)op = w0;
    *(float4*)(op + 4) = w1;
  }
}

// Wave-private double-buffered LDS pipeline. Block = 4 waves, one k, 16 r's
// (4 per wave). Chunk = 16 c's: 4KB W-tile + 2KB x-tile staged via
// global_load_lds (6 instrs); compute = 48 ds_read_b128 + 512 FMA per lane
// group. Counted vmcnt(6): next chunk's loads stay in flight during compute.
// No barriers anywhere (each wave owns its own buffers).
__global__ __launch_bounds__(256, 2) void priors_gemm(const float* __restrict__ xT,
                                                      const float* __restrict__ W,
                                                      __hip_bfloat16* __restrict__ priors,
                                                      float* __restrict__ s0) {
  __shared__ float lds[4][2][1536];  // per wave, per buffer: W[16][64] | x[16][32]
  const int w = threadIdx.x >> 6, lane = threadIdx.x & 63;
  const int bg = lane >> 3, og = lane & 7;
  const int k = blockIdx.x & 15, rblk = blockIdx.x >> 4;  // consecutive bids share x rblk
  const int rbase = rblk * 16 + w * 4;
  const int laneoff = lane * 4;  // floats (16B per lane)

  float acc[4][8];
  float s0acc[4][8];
#pragma unroll
  for (int i = 0; i < 4; ++i)
#pragma unroll
    for (int j = 0; j < 8; ++j) s0acc[i][j] = 0.f;

  auto stage = [&](int t, int buf) {
    const int r = rbase + (t >> 2);
    const int c0 = (t & 3) * 16;
    const float* wsrc = W + ((size_t)(k * NR + r)) * (NC * NO) + c0 * NO + laneoff;
    const float* xsrc = xT + ((size_t)r * NC + c0) * NB + laneoff;
    float* dst = &lds[w][buf][0];
#pragma unroll
    for (int i = 0; i < 4; ++i) gload_lds16(wsrc + i * 256, dst + i * 256);
#pragma unroll
    for (int i = 0; i < 2; ++i) gload_lds16(xsrc + i * 256, dst + 1024 + i * 256);
  };

  auto compute = [&](int t) {
    const int buf = t & 1;
    const float* bw = &lds[w][buf][0];
    const float* bx = &lds[w][buf][1024];
    if ((t & 3) == 0) {
#pragma unroll
      for (int i = 0; i < 4; ++i)
#pragma unroll
        for (int j = 0; j < 8; ++j) acc[i][j] = 0.f;
    }
#pragma unroll
    for (int c = 0; c < 16; ++c) {
      float4 xv = *(const float4*)(bx + c * 32 + bg * 4);
      float4 wa = *(const float4*)(bw + c * 64 + og * 8);
      float4 wb = *(const float4*)(bw + c * 64 + og * 8 + 4);
      float xr[4] = {xv.x, xv.y, xv.z, xv.w};
      float wr[8] = {wa.x, wa.y, wa.z, wa.w, wb.x, wb.y, wb.z, wb.w};
#pragma unroll
      for (int i = 0; i < 4; ++i)
#pragma unroll
        for (int j = 0; j < 8; ++j) acc[i][j] = fmaf(xr[i], wr[j], acc[i][j]);
    }
    if ((t & 3) == 3) {
      const int r = rbase + (t >> 2);
#pragma unroll
      for (int i = 0; i < 4; ++i) {
        uint4 uv;
        uv.x = packbf2(acc[i][0], acc[i][1]);
        uv.y = packbf2(acc[i][2], acc[i][3]);
        uv.z = packbf2(acc[i][4], acc[i][5]);
        uv.w = packbf2(acc[i][6], acc[i][7]);
        __hip_bfloat16* pp = priors + (((size_t)(k * NB + bg * 4 + i) * NR) + r) * NO + og * 8;
        *(uint4*)pp = uv;
#pragma unroll
        for (int j = 0; j < 8; ++j) s0acc[i][j] += acc[i][j];
      }
    }
  };

  stage(0, 0);
  stage(1, 1);

  for (int t = 0; t < 15; ++t) {
    WAIT_VMCNT6;        // chunk t's 6 loads retired; chunk t+1's stay in flight
    compute(t);
    WAIT_LGKM0;         // ds_reads of buf done before overwriting it
    if (t < 14) stage(t + 2, t & 1);
  }
  WAIT_VMCNT0;
  compute(15);

#pragma unroll
  for (int i = 0; i < 4; ++i)
#pragma unroll
    for (int j = 0; j < 8; ++j)
      atomicAdd(&s0[(k * NB + bg * 4 + i) * NO + og * 8 + j], s0acc[i][j]);
}

// Routing pass. Block per (k,b). Lane: g = lane/8 (r within group-of-8), sl = lane%8 (o-slice of 8).
// PASS==1: l = a_r = p.o0 (o0 computed in-block from s0); stores a_r; writes o1.
// PASS==2: l = a_r + p.o1; writes final output.
template <int PASS>
__global__ __launch_bounds__(256) void routing(const __hip_bfloat16* __restrict__ priors,
                                               const float* __restrict__ s0,
                                               float* __restrict__ Abuf,
                                               const float* __restrict__ o_prev,
                                               float* __restrict__ o_out) {
  __shared__ float o_lds[64];
  __shared__ float red_num[4][8][8];
  __shared__ float red_den[4];
  const int kb = blockIdx.x;
  const int tid = threadIdx.x, w = tid >> 6, lane = tid & 63;

  if (tid < 64) {
    float ov;
    if (PASS == 1) {
      float s = s0[kb * 64 + tid] * (1.f / (float)NR);
      float sq = s * s;
#pragma unroll
      for (int m = 1; m < 64; m <<= 1) sq += __shfl_xor(sq, m, 64);
      ov = (sq / (1.f + sq)) * rsqrtf(sq) * s;  // squash
    } else {
      ov = o_prev[kb * 64 + tid];
    }
    o_lds[tid] = ov;
  }
  __syncthreads();

  const int g = lane >> 3, sl = lane & 7;
  float os[8];
#pragma unroll
  for (int j = 0; j < 8; ++j) os[j] = o_lds[sl * 8 + j];

  float num[8];
#pragma unroll
  for (int j = 0; j < 8; ++j) num[j] = 0.f;
  float den = 0.f;

  const __hip_bfloat16* pbase = priors + (size_t)kb * (NR * NO);
  const int rsub = w * 8 + g;
  float* ab = Abuf + (size_t)kb * NR;

  for (int it = 0; it < NR / 32; ++it) {
    const int r = it * 32 + rsub;
    uint4 pv = *(const uint4*)(pbase + (size_t)r * NO + sl * 8);
    float f[8];
    f[0] = __builtin_bit_cast(float, pv.x << 16);
    f[1] = __builtin_bit_cast(float, pv.x & 0xffff0000u);
    f[2] = __builtin_bit_cast(float, pv.y << 16);
    f[3] = __builtin_bit_cast(float, pv.y & 0xffff0000u);
    f[4] = __builtin_bit_cast(float, pv.z << 16);
    f[5] = __builtin_bit_cast(float, pv.z & 0xffff0000u);
    f[6] = __builtin_bit_cast(float, pv.w << 16);
    f[7] = __builtin_bit_cast(float, pv.w & 0xffff0000u);

    float d = 0.f;
#pragma unroll
    for (int j = 0; j < 8; ++j) d = fmaf(f[j], os[j], d);
#pragma unroll
    for (int m = 1; m < 8; m <<= 1) d += __shfl_xor(d, m, 64);  // dot over the 8-lane group

    float lg;
    if (PASS == 1) {
      lg = d;
      if (sl == 0) ab[r] = d;
    } else {
      lg = d + ab[r];
    }
    float e = __expf(lg);  // args |lg| < ~0.1, no max-subtraction needed
    den += e;
#pragma unroll
    for (int j = 0; j < 8; ++j) num[j] = fmaf(e, f[j], num[j]);
  }

#pragma unroll
  for (int m = 8; m < 64; m <<= 1) {
    den += __shfl_xor(den, m, 64);
#pragma unroll
    for (int j = 0; j < 8; ++j) num[j] += __shfl_xor(num[j], m, 64);
  }
  if (lane < 8) {
#pragma unroll
    for (int j = 0; j < 8; ++j) red_num[w][lane][j] = num[j];
    if (lane == 0) red_den[w] = den;
  }
  __syncthreads();

  if (tid < 64) {
    const int s_ = tid >> 3, j_ = tid & 7;
    float nm = red_num[0][s_][j_] + red_num[1][s_][j_] + red_num[2][s_][j_] + red_num[3][s_][j_];
    float dn = red_den[0] + red_den[1] + red_den[2] + red_den[3];
    float sv = nm / dn;
    float sq = sv * sv;
#pragma unroll
    for (int m = 1; m < 64; m <<= 1) sq += __shfl_xor(sq, m, 64);
    float ov = (sq / (1.f + sq)) * rsqrtf(sq) * sv;
    o_out[kb * 64 + tid] = ov;
  }
}

extern "C" void kernel_launch(void* const* d_in, const int* in_sizes, int n_in,
                              void* d_out, int out_size, void* d_ws, size_t ws_size,
                              hipStream_t stream) {
  const float* x = (const float*)d_in[0];          // [B][R][CIN]
  const float* W = (const float*)d_in[1];          // [K][R][CIN][COUT]
  float* out = (float*)d_out;                      // [K][B][COUT]
  char* ws = (char*)d_ws;

  size_t off = 0;
  float* xT = (float*)(ws + off);                  off += (size_t)NR * NC * NB * 4;        // 16 MB
  __hip_bfloat16* priors = (__hip_bfloat16*)(ws + off); off += (size_t)NK * NB * NR * NO * 2; // 128 MB
  float* s0 = (float*)(ws + off);                  off += (size_t)NK * NB * NO * 4;        // 128 KB
  float* o1 = (float*)(ws + off);                  off += (size_t)NK * NB * NO * 4;        // 128 KB
  float* Abuf = (float*)(ws + off);                off += (size_t)NK * NB * NR * 4;        // 4 MB

  hipMemsetAsync(s0, 0, (size_t)NK * NB * NO * sizeof(float), stream);
  transpose_x<<<NR, 256, 0, stream>>>(x, xT);
  priors_gemm<<<(NR / 16) * NK, 256, 0, stream>>>(xT, W, priors, s0);
  routing<1><<<NK * NB, 256, 0, stream>>>(priors, s0, Abuf, nullptr, o1);
  routing<2><<<NK * NB, 256, 0, stream>>>(priors, s0, Abuf, o1, out);
}

// Round 3
// 392.603 us; speedup vs baseline: 1.5878x; 1.5878x over previous
//
#include <hip/hip_runtime.h>
#include <hip/hip_bf16.h>
#include <stdint.h>

#define NB 32
#define NR 2048
#define NC 64
#define NO 64
#define NK 16

__device__ __forceinline__ uint32_t f2bf(float f) {
  uint32_t u = __builtin_bit_cast(uint32_t, f);
  return (u + 0x7fffu + ((u >> 16) & 1u)) >> 16;  // RNE
}
__device__ __forceinline__ uint32_t packbf2(float lo, float hi) {
  return f2bf(lo) | (f2bf(hi) << 16);
}

// x[b][r][c] -> xT[r][c][b]
__global__ __launch_bounds__(256) void transpose_x(const float* __restrict__ x,
                                                   float* __restrict__ xT) {
  __shared__ float tile[32][65];
  const int r = blockIdx.x, t = threadIdx.x;
  {
    const int b = t >> 3, c0 = (t & 7) << 3;
    const float* xp = x + ((size_t)b * NR + r) * NC + c0;
    float4 v0 = *(const float4*)xp;
    float4 v1 = *(const float4*)(xp + 4);
    tile[b][c0 + 0] = v0.x; tile[b][c0 + 1] = v0.y; tile[b][c0 + 2] = v0.z; tile[b][c0 + 3] = v0.w;
    tile[b][c0 + 4] = v1.x; tile[b][c0 + 5] = v1.y; tile[b][c0 + 6] = v1.z; tile[b][c0 + 7] = v1.w;
  }
  __syncthreads();
  {
    const int c = t >> 2, b0 = (t & 3) << 3;
    float4 w0 = make_float4(tile[b0 + 0][c], tile[b0 + 1][c], tile[b0 + 2][c], tile[b0 + 3][c]);
    float4 w1 = make_float4(tile[b0 + 4][c], tile[b0 + 5][c], tile[b0 + 6][c], tile[b0 + 7][c]);
    float* op = xT + ((size_t)r * NC + c) * NB + b0;
    *(float4*)op = w0;
    *(float4*)(op + 4) = w1;
  }
}

// One wave per (k, r). Register-double-buffered W/x streaming, no LDS, no
// barriers, no atomics. Chunk = 4 c's = 12 float4 loads in flight while the
// other chunk's 128 FMAs execute. bid maps all 16 k's of one r adjacently
// so the xT row stays L2/L3-hot.
#define LOADC(X, WA, WB, c0)                                        \
  do {                                                              \
    _Pragma("unroll") for (int i = 0; i < 4; ++i) {                 \
      X[i]  = *(const float4*)(xp + ((c0) + i) * NB);               \
      WA[i] = *(const float4*)(wp + ((c0) + i) * NO);               \
      WB[i] = *(const float4*)(wp + ((c0) + i) * NO + 4);           \
    }                                                               \
  } while (0)

#define COMPC(X, WA, WB)                                            \
  do {                                                              \
    _Pragma("unroll") for (int i = 0; i < 4; ++i) {                 \
      float xr[4] = {X[i].x, X[i].y, X[i].z, X[i].w};               \
      float wr[8] = {WA[i].x, WA[i].y, WA[i].z, WA[i].w,            \
                     WB[i].x, WB[i].y, WB[i].z, WB[i].w};           \
      _Pragma("unroll") for (int a = 0; a < 4; ++a)                 \
        _Pragma("unroll") for (int b = 0; b < 8; ++b)               \
          acc[a][b] = fmaf(xr[a], wr[b], acc[a][b]);                \
    }                                                               \
  } while (0)

__global__ __launch_bounds__(256, 3) void priors_gemm(const float* __restrict__ xT,
                                                      const float* __restrict__ W,
                                                      __hip_bfloat16* __restrict__ priors) {
  const int w = threadIdx.x >> 6, lane = threadIdx.x & 63;
  const int bg = lane >> 3, og = lane & 7;
  const int k = (blockIdx.x & 3) * 4 + w;
  const int r = blockIdx.x >> 2;

  const float* wp = W + ((size_t)k * NR + r) * (NC * NO) + og * 8;
  const float* xp = xT + (size_t)r * (NC * NB) + bg * 4;

  float acc[4][8];
#pragma unroll
  for (int i = 0; i < 4; ++i)
#pragma unroll
    for (int j = 0; j < 8; ++j) acc[i][j] = 0.f;

  float4 xA[4], waA[4], wbA[4];
  float4 xB[4], waB[4], wbB[4];

  LOADC(xA, waA, wbA, 0);
  LOADC(xB, waB, wbB, 4);
#pragma unroll
  for (int t = 0; t < 8; ++t) {
    COMPC(xA, waA, wbA);
    if (t < 7) LOADC(xA, waA, wbA, t * 8 + 8);
    COMPC(xB, waB, wbB);
    if (t < 7) LOADC(xB, waB, wbB, t * 8 + 12);
  }

#pragma unroll
  for (int i = 0; i < 4; ++i) {
    uint4 uv;
    uv.x = packbf2(acc[i][0], acc[i][1]);
    uv.y = packbf2(acc[i][2], acc[i][3]);
    uv.z = packbf2(acc[i][4], acc[i][5]);
    uv.w = packbf2(acc[i][6], acc[i][7]);
    __hip_bfloat16* pp = priors + (((size_t)(k * NB + bg * 4 + i) * NR) + r) * NO + og * 8;
    *(uint4*)pp = uv;
  }
}

// Routing pass. Block per (k,b). Lane: g = lane/8 (r within group-of-8), sl = lane%8 (o-slice of 8).
// PASS==1: phase A computes o0 = squash(mean_r p) in-block (priors read #1);
//          phase B: l = a_r = p.o0, stores a_r, writes o1 (priors read #2, L3-hot).
// PASS==2: l = a_r + p.o1; writes final output.
template <int PASS>
__global__ __launch_bounds__(256) void routing(const __hip_bfloat16* __restrict__ priors,
                                               float* __restrict__ Abuf,
                                               const float* __restrict__ o_prev,
                                               float* __restrict__ o_out) {
  __shared__ float o_lds[64];
  __shared__ float red_num[4][8][8];
  __shared__ float red_den[4];
  const int kb = blockIdx.x;
  const int tid = threadIdx.x, w = tid >> 6, lane = tid & 63;
  const int g = lane >> 3, sl = lane & 7;
  const int rsub = w * 8 + g;
  const __hip_bfloat16* pbase = priors + (size_t)kb * (NR * NO);
  float* ab = Abuf + (size_t)kb * NR;

  if (PASS == 1) {
    // phase A: column-sum over r -> mean -> squash -> o0
    float sum[8];
#pragma unroll
    for (int j = 0; j < 8; ++j) sum[j] = 0.f;
    for (int it = 0; it < NR / 32; ++it) {
      const int r = it * 32 + rsub;
      uint4 pv = *(const uint4*)(pbase + (size_t)r * NO + sl * 8);
      sum[0] += __builtin_bit_cast(float, pv.x << 16);
      sum[1] += __builtin_bit_cast(float, pv.x & 0xffff0000u);
      sum[2] += __builtin_bit_cast(float, pv.y << 16);
      sum[3] += __builtin_bit_cast(float, pv.y & 0xffff0000u);
      sum[4] += __builtin_bit_cast(float, pv.z << 16);
      sum[5] += __builtin_bit_cast(float, pv.z & 0xffff0000u);
      sum[6] += __builtin_bit_cast(float, pv.w << 16);
      sum[7] += __builtin_bit_cast(float, pv.w & 0xffff0000u);
    }
#pragma unroll
    for (int m = 8; m < 64; m <<= 1)
#pragma unroll
      for (int j = 0; j < 8; ++j) sum[j] += __shfl_xor(sum[j], m, 64);
    if (lane < 8) {
#pragma unroll
      for (int j = 0; j < 8; ++j) red_num[w][lane][j] = sum[j];
    }
    __syncthreads();
    if (tid < 64) {
      const int s_ = tid >> 3, j_ = tid & 7;
      float sv = (red_num[0][s_][j_] + red_num[1][s_][j_] +
                  red_num[2][s_][j_] + red_num[3][s_][j_]) * (1.f / (float)NR);
      float sq = sv * sv;
#pragma unroll
      for (int m = 1; m < 64; m <<= 1) sq += __shfl_xor(sq, m, 64);
      o_lds[tid] = (sq / (1.f + sq)) * rsqrtf(sq) * sv;  // squash
    }
    __syncthreads();
  } else {
    if (tid < 64) o_lds[tid] = o_prev[kb * 64 + tid];
    __syncthreads();
  }

  float os[8];
#pragma unroll
  for (int j = 0; j < 8; ++j) os[j] = o_lds[sl * 8 + j];

  float num[8];
#pragma unroll
  for (int j = 0; j < 8; ++j) num[j] = 0.f;
  float den = 0.f;

  for (int it = 0; it < NR / 32; ++it) {
    const int r = it * 32 + rsub;
    uint4 pv = *(const uint4*)(pbase + (size_t)r * NO + sl * 8);
    float f[8];
    f[0] = __builtin_bit_cast(float, pv.x << 16);
    f[1] = __builtin_bit_cast(float, pv.x & 0xffff0000u);
    f[2] = __builtin_bit_cast(float, pv.y << 16);
    f[3] = __builtin_bit_cast(float, pv.y & 0xffff0000u);
    f[4] = __builtin_bit_cast(float, pv.z << 16);
    f[5] = __builtin_bit_cast(float, pv.z & 0xffff0000u);
    f[6] = __builtin_bit_cast(float, pv.w << 16);
    f[7] = __builtin_bit_cast(float, pv.w & 0xffff0000u);

    float d = 0.f;
#pragma unroll
    for (int j = 0; j < 8; ++j) d = fmaf(f[j], os[j], d);
#pragma unroll
    for (int m = 1; m < 8; m <<= 1) d += __shfl_xor(d, m, 64);  // dot over the 8-lane group

    float lg;
    if (PASS == 1) {
      lg = d;
      if (sl == 0) ab[r] = d;
    } else {
      lg = d + ab[r];
    }
    float e = __expf(lg);  // |lg| << 1, no max-subtraction needed
    den += e;
#pragma unroll
    for (int j = 0; j < 8; ++j) num[j] = fmaf(e, f[j], num[j]);
  }

#pragma unroll
  for (int m = 8; m < 64; m <<= 1) {
    den += __shfl_xor(den, m, 64);
#pragma unroll
    for (int j = 0; j < 8; ++j) num[j] += __shfl_xor(num[j], m, 64);
  }
  if (lane < 8) {
#pragma unroll
    for (int j = 0; j < 8; ++j) red_num[w][lane][j] = num[j];
    if (lane == 0) red_den[w] = den;
  }
  __syncthreads();

  if (tid < 64) {
    const int s_ = tid >> 3, j_ = tid & 7;
    float nm = red_num[0][s_][j_] + red_num[1][s_][j_] + red_num[2][s_][j_] + red_num[3][s_][j_];
    float dn = red_den[0] + red_den[1] + red_den[2] + red_den[3];
    float sv = nm / dn;
    float sq = sv * sv;
#pragma unroll
    for (int m = 1; m < 64; m <<= 1) sq += __shfl_xor(sq, m, 64);
    float ov = (sq / (1.f + sq)) * rsqrtf(sq) * sv;
    o_out[kb * 64 + tid] = ov;
  }
}

extern "C" void kernel_launch(void* const* d_in, const int* in_sizes, int n_in,
                              void* d_out, int out_size, void* d_ws, size_t ws_size,
                              hipStream_t stream) {
  const float* x = (const float*)d_in[0];          // [B][R][CIN]
  const float* W = (const float*)d_in[1];          // [K][R][CIN][COUT]
  float* out = (float*)d_out;                      // [K][B][COUT]
  char* ws = (char*)d_ws;

  size_t off = 0;
  float* xT = (float*)(ws + off);                  off += (size_t)NR * NC * NB * 4;        // 16 MB
  __hip_bfloat16* priors = (__hip_bfloat16*)(ws + off); off += (size_t)NK * NB * NR * NO * 2; // 128 MB
  float* o1 = (float*)(ws + off);                  off += (size_t)NK * NB * NO * 4;        // 128 KB
  float* Abuf = (float*)(ws + off);                off += (size_t)NK * NB * NR * 4;        // 4 MB

  transpose_x<<<NR, 256, 0, stream>>>(x, xT);
  priors_gemm<<<NR * 4, 256, 0, stream>>>(xT, W, priors);
  routing<1><<<NK * NB, 256, 0, stream>>>(priors, Abuf, nullptr, o1);
  routing<2><<<NK * NB, 256, 0, stream>>>(priors, Abuf, o1, out);
}

// Round 4
// 249.581 us; speedup vs baseline: 2.4977x; 1.5731x over previous
//
#include <hip/hip_runtime.h>
#include <hip/hip_bf16.h>
#include <stdint.h>

#define NB 32
#define NR 2048
#define NC 64
#define NO 64
#define NK 16
#define CHC 8                 // c's per chunk
#define NCHUNK (NC / CHC)     // 8 chunks

__device__ __forceinline__ uint32_t f2bf(float f) {
  uint32_t u = __builtin_bit_cast(uint32_t, f);
  return (u + 0x7fffu + ((u >> 16) & 1u)) >> 16;  // RNE
}
__device__ __forceinline__ uint32_t packbf2(float lo, float hi) {
  return f2bf(lo) | (f2bf(hi) << 16);
}

__device__ __forceinline__ void gload_lds16(const float* g, float* l) {
  __builtin_amdgcn_global_load_lds(
      (const __attribute__((address_space(1))) void*)g,
      (__attribute__((address_space(3))) void*)l, 16, 0, 0);
}

// x[b][r][c] -> xT[r][c][b]
__global__ __launch_bounds__(256) void transpose_x(const float* __restrict__ x,
                                                   float* __restrict__ xT) {
  __shared__ float tile[32][65];
  const int r = blockIdx.x, t = threadIdx.x;
  {
    const int b = t >> 3, c0 = (t & 7) << 3;
    const float* xp = x + ((size_t)b * NR + r) * NC + c0;
    float4 v0 = *(const float4*)xp;
    float4 v1 = *(const float4*)(xp + 4);
    tile[b][c0 + 0] = v0.x; tile[b][c0 + 1] = v0.y; tile[b][c0 + 2] = v0.z; tile[b][c0 + 3] = v0.w;
    tile[b][c0 + 4] = v1.x; tile[b][c0 + 5] = v1.y; tile[b][c0 + 6] = v1.z; tile[b][c0 + 7] = v1.w;
  }
  __syncthreads();
  {
    const int c = t >> 2, b0 = (t & 3) << 3;
    float4 w0 = make_float4(tile[b0 + 0][c], tile[b0 + 1][c], tile[b0 + 2][c], tile[b0 + 3][c]);
    float4 w1 = make_float4(tile[b0 + 4][c], tile[b0 + 5][c], tile[b0 + 6][c], tile[b0 + 7][c]);
    float* op = xT + ((size_t)r * NC + c) * NB + b0;
    *(float4*)op = w0;
    *(float4*)(op + 4) = w1;
  }
}

// m97-structure streaming GEMM. Block = (k, 4 r's), wave w computes r=rbase+w
// (full 32b x 64o output in acc[4][8]). Per chunk (8 c's): all 4 waves
// cooperatively stage W (8KB) + x (4KB) lane-contiguously via global_load_lds
// (3 instrs/thread, 1KB distinct each), then { stage(t+1); compute(t); barrier }.
// Compiler inserts the vmcnt/lgkm drains at the barrier (m97-proven).
__global__ __launch_bounds__(256, 3) void priors_gemm(const float* __restrict__ xT,
                                                      const float* __restrict__ W,
                                                      __hip_bfloat16* __restrict__ priors) {
  __shared__ float ldsW[2][4][CHC][64];  // [buf][r'][c][o]  2 x 8KB
  __shared__ float ldsX[2][4][CHC][32];  // [buf][r'][c][b]  2 x 4KB
  const int w = threadIdx.x >> 6, lane = threadIdx.x & 63;
  const int bg = lane >> 3, og = lane & 7;
  const int k = blockIdx.x & 15;             // 16 k's of one rquad adjacent -> xT L2-hot
  const int rbase = (blockIdx.x >> 4) * 4;
  const int r = rbase + w;

  // W src for staging: instr i covers row rbase + i*2 + (w>>1),
  // cols [c0 + (w&1)*4, +4) x all 64 o, lane-contiguous 16B.
  const float* wsrc = W + ((size_t)(k * NR + rbase + (w >> 1))) * (NC * NO)
                        + (w & 1) * 256 + lane * 4;
  // x src: wave w stages its own row r, [8 c][32 b] contiguous.
  const float* xsrc = xT + ((size_t)r * NC) * NB + lane * 4;

  float acc[4][8] = {};

  auto stage = [&](int t, int buf) {
    const int c0 = t * CHC;
    float* dw = &ldsW[buf][0][0][0] + w * 256;
#pragma unroll
    for (int i = 0; i < 2; ++i)
      gload_lds16(wsrc + (size_t)i * 2 * (NC * NO) + c0 * 64, dw + i * 1024);
    gload_lds16(xsrc + c0 * 32, &ldsX[buf][0][0][0] + w * 256);
  };

  auto compute = [&](int buf) {
#pragma unroll
    for (int c = 0; c < CHC; ++c) {
      float4 xv = *(const float4*)&ldsX[buf][w][c][bg * 4];
      float4 wa = *(const float4*)&ldsW[buf][w][c][og * 8];
      float4 wb = *(const float4*)&ldsW[buf][w][c][og * 8 + 4];
      float xr[4] = {xv.x, xv.y, xv.z, xv.w};
      float wr[8] = {wa.x, wa.y, wa.z, wa.w, wb.x, wb.y, wb.z, wb.w};
#pragma unroll
      for (int a = 0; a < 4; ++a)
#pragma unroll
        for (int b = 0; b < 8; ++b) acc[a][b] = fmaf(xr[a], wr[b], acc[a][b]);
    }
  };

  stage(0, 0);
  __syncthreads();
#pragma unroll
  for (int t = 0; t < NCHUNK; ++t) {
    if (t + 1 < NCHUNK) stage(t + 1, (t + 1) & 1);  // prefetch next chunk
    compute(t & 1);                                  // ds_read + FMA current
    __syncthreads();                                 // drain prefetch, swap
  }

#pragma unroll
  for (int i = 0; i < 4; ++i) {
    uint4 uv;
    uv.x = packbf2(acc[i][0], acc[i][1]);
    uv.y = packbf2(acc[i][2], acc[i][3]);
    uv.z = packbf2(acc[i][4], acc[i][5]);
    uv.w = packbf2(acc[i][6], acc[i][7]);
    __hip_bfloat16* pp = priors + (((size_t)(k * NB + bg * 4 + i) * NR) + r) * NO + og * 8;
    *(uint4*)pp = uv;
  }
}

// Routing pass. Block per (k,b). Lane: g = lane/8 (r within group-of-8), sl = lane%8 (o-slice of 8).
// PASS==1: phase A computes o0 = squash(mean_r p) in-block (priors read #1);
//          phase B: l = a_r = p.o0, stores a_r, writes o1 (priors read #2, L3-hot).
// PASS==2: l = a_r + p.o1; writes final output.
template <int PASS>
__global__ __launch_bounds__(256) void routing(const __hip_bfloat16* __restrict__ priors,
                                               float* __restrict__ Abuf,
                                               const float* __restrict__ o_prev,
                                               float* __restrict__ o_out) {
  __shared__ float o_lds[64];
  __shared__ float red_num[4][8][8];
  __shared__ float red_den[4];
  const int kb = blockIdx.x;
  const int tid = threadIdx.x, w = tid >> 6, lane = tid & 63;
  const int g = lane >> 3, sl = lane & 7;
  const int rsub = w * 8 + g;
  const __hip_bfloat16* pbase = priors + (size_t)kb * (NR * NO);
  float* ab = Abuf + (size_t)kb * NR;

  if (PASS == 1) {
    // phase A: column-sum over r -> mean -> squash -> o0
    float sum[8];
#pragma unroll
    for (int j = 0; j < 8; ++j) sum[j] = 0.f;
    for (int it = 0; it < NR / 32; ++it) {
      const int r = it * 32 + rsub;
      uint4 pv = *(const uint4*)(pbase + (size_t)r * NO + sl * 8);
      sum[0] += __builtin_bit_cast(float, pv.x << 16);
      sum[1] += __builtin_bit_cast(float, pv.x & 0xffff0000u);
      sum[2] += __builtin_bit_cast(float, pv.y << 16);
      sum[3] += __builtin_bit_cast(float, pv.y & 0xffff0000u);
      sum[4] += __builtin_bit_cast(float, pv.z << 16);
      sum[5] += __builtin_bit_cast(float, pv.z & 0xffff0000u);
      sum[6] += __builtin_bit_cast(float, pv.w << 16);
      sum[7] += __builtin_bit_cast(float, pv.w & 0xffff0000u);
    }
#pragma unroll
    for (int m = 8; m < 64; m <<= 1)
#pragma unroll
      for (int j = 0; j < 8; ++j) sum[j] += __shfl_xor(sum[j], m, 64);
    if (lane < 8) {
#pragma unroll
      for (int j = 0; j < 8; ++j) red_num[w][lane][j] = sum[j];
    }
    __syncthreads();
    if (tid < 64) {
      const int s_ = tid >> 3, j_ = tid & 7;
      float sv = (red_num[0][s_][j_] + red_num[1][s_][j_] +
                  red_num[2][s_][j_] + red_num[3][s_][j_]) * (1.f / (float)NR);
      float sq = sv * sv;
#pragma unroll
      for (int m = 1; m < 64; m <<= 1) sq += __shfl_xor(sq, m, 64);
      o_lds[tid] = (sq / (1.f + sq)) * rsqrtf(sq) * sv;  // squash
    }
    __syncthreads();
  } else {
    if (tid < 64) o_lds[tid] = o_prev[kb * 64 + tid];
    __syncthreads();
  }

  float os[8];
#pragma unroll
  for (int j = 0; j < 8; ++j) os[j] = o_lds[sl * 8 + j];

  float num[8];
#pragma unroll
  for (int j = 0; j < 8; ++j) num[j] = 0.f;
  float den = 0.f;

  for (int it = 0; it < NR / 32; ++it) {
    const int r = it * 32 + rsub;
    uint4 pv = *(const uint4*)(pbase + (size_t)r * NO + sl * 8);
    float f[8];
    f[0] = __builtin_bit_cast(float, pv.x << 16);
    f[1] = __builtin_bit_cast(float, pv.x & 0xffff0000u);
    f[2] = __builtin_bit_cast(float, pv.y << 16);
    f[3] = __builtin_bit_cast(float, pv.y & 0xffff0000u);
    f[4] = __builtin_bit_cast(float, pv.z << 16);
    f[5] = __builtin_bit_cast(float, pv.z & 0xffff0000u);
    f[6] = __builtin_bit_cast(float, pv.w << 16);
    f[7] = __builtin_bit_cast(float, pv.w & 0xffff0000u);

    float d = 0.f;
#pragma unroll
    for (int j = 0; j < 8; ++j) d = fmaf(f[j], os[j], d);
#pragma unroll
    for (int m = 1; m < 8; m <<= 1) d += __shfl_xor(d, m, 64);  // dot over the 8-lane group

    float lg;
    if (PASS == 1) {
      lg = d;
      if (sl == 0) ab[r] = d;
    } else {
      lg = d + ab[r];
    }
    float e = __expf(lg);  // |lg| << 1, no max-subtraction needed
    den += e;
#pragma unroll
    for (int j = 0; j < 8; ++j) num[j] = fmaf(e, f[j], num[j]);
  }

#pragma unroll
  for (int m = 8; m < 64; m <<= 1) {
    den += __shfl_xor(den, m, 64);
#pragma unroll
    for (int j = 0; j < 8; ++j) num[j] += __shfl_xor(num[j], m, 64);
  }
  if (lane < 8) {
#pragma unroll
    for (int j = 0; j < 8; ++j) red_num[w][lane][j] = num[j];
    if (lane == 0) red_den[w] = den;
  }
  __syncthreads();

  if (tid < 64) {
    const int s_ = tid >> 3, j_ = tid & 7;
    float nm = red_num[0][s_][j_] + red_num[1][s_][j_] + red_num[2][s_][j_] + red_num[3][s_][j_];
    float dn = red_den[0] + red_den[1] + red_den[2] + red_den[3];
    float sv = nm / dn;
    float sq = sv * sv;
#pragma unroll
    for (int m = 1; m < 64; m <<= 1) sq += __shfl_xor(sq, m, 64);
    float ov = (sq / (1.f + sq)) * rsqrtf(sq) * sv;
    o_out[kb * 64 + tid] = ov;
  }
}

extern "C" void kernel_launch(void* const* d_in, const int* in_sizes, int n_in,
                              void* d_out, int out_size, void* d_ws, size_t ws_size,
                              hipStream_t stream) {
  const float* x = (const float*)d_in[0];          // [B][R][CIN]
  const float* W = (const float*)d_in[1];          // [K][R][CIN][COUT]
  float* out = (float*)d_out;                      // [K][B][COUT]
  char* ws = (char*)d_ws;

  size_t off = 0;
  float* xT = (float*)(ws + off);                  off += (size_t)NR * NC * NB * 4;        // 16 MB
  __hip_bfloat16* priors = (__hip_bfloat16*)(ws + off); off += (size_t)NK * NB * NR * NO * 2; // 128 MB
  float* o1 = (float*)(ws + off);                  off += (size_t)NK * NB * NO * 4;        // 128 KB
  float* Abuf = (float*)(ws + off);                off += (size_t)NK * NB * NR * 4;        // 4 MB

  transpose_x<<<NR, 256, 0, stream>>>(x, xT);
  priors_gemm<<<(NR / 4) * NK, 256, 0, stream>>>(xT, W, priors);
  routing<1><<<NK * NB, 256, 0, stream>>>(priors, Abuf, nullptr, o1);
  routing<2><<<NK * NB, 256, 0, stream>>>(priors, Abuf, o1, out);
}